// Round 6
// baseline (58252.399 us; speedup 1.0000x reference)
//
#include <hip/hip_runtime.h>
#include <hip/hip_fp16.h>
#include <math.h>

#define NBLK 256
#define NTHR 1024

__device__ __forceinline__ float fast_rcp(float x) {
#if __has_builtin(__builtin_amdgcn_rcpf)
  return __builtin_amdgcn_rcpf(x);
#else
  return 1.f / x;
#endif
}
__device__ __forceinline__ float fast_sigmoid(float x) { return fast_rcp(1.f + __expf(-x)); }
__device__ __forceinline__ float fast_tanh(float x) { return 1.f - 2.f * fast_rcp(1.f + __expf(2.f * x)); }

union HU2 { unsigned int u; __half2 h; };
union HU4 { uint4 u; __half2 h[4]; };
__device__ __forceinline__ float2 cvt2(unsigned int u) { HU2 t; t.u = u; return __half22float2(t.h); }

__device__ __forceinline__ void sta(float* p, float v) {
  __hip_atomic_store(p, v, __ATOMIC_RELAXED, __HIP_MEMORY_SCOPE_AGENT);
}
__device__ __forceinline__ float lda(const float* p) {
  return __hip_atomic_load(p, __ATOMIC_RELAXED, __HIP_MEMORY_SCOPE_AGENT);
}
__device__ __forceinline__ int ldai(const int* p) {
  return __hip_atomic_load(p, __ATOMIC_RELAXED, __HIP_MEMORY_SCOPE_AGENT);
}
__device__ __forceinline__ void ntst(float* p, float v) { __builtin_nontemporal_store(v, p); }

struct Params {
  const float *enc, *pre_w1, *pre_w2, *attn_bi, *attn_bh;
  const float *q_w, *k_w, *score_w, *score_b, *conv_w, *loc_w, *loc_b;
  const float *out_bi, *out_bh, *dec_b, *gate_b;
  const float *attn_wi, *attn_wh, *out_wi, *out_wh, *dec_w, *gate_w;
  const int *text_lens, *mel_lens;
  __half *hkeys, *gw1T, *gw2T, *decT, *pre1T, *pre2T, *gateh, *locwh, *qwT;
  float *hA, *hO, *attw, *attcum, *decin, *ebuf, *zpart, *ctxacc, *ctxacc2, *stateZ;
  float *qacc1, *qacc2;
  int *done, *zdone, *done2, *hAdone;
  float *out_mel, *out_gate, *out_attn, *out_mask;
};

// ---------------- prep: keys GEMM (fp16 out) ----------------
__global__ __launch_bounds__(512) void k_keys(Params p) {
  __shared__ float sA[16][132];
  __shared__ float sB[16][68];
  int tid = threadIdx.x;
  int row0 = blockIdx.x * 128, col0 = blockIdx.y * 64;
  float acc[4][4] = {};
  int r = tid >> 2, kq = tid & 3;
  int tx = tid & 15, ty = tid >> 4;
  for (int k0 = 0; k0 < 1024; k0 += 16) {
    __syncthreads();
    float4 a4 = *(const float4*)(p.enc + (size_t)(row0 + r) * 1024 + k0 + kq * 4);
    sA[kq * 4 + 0][r] = a4.x; sA[kq * 4 + 1][r] = a4.y;
    sA[kq * 4 + 2][r] = a4.z; sA[kq * 4 + 3][r] = a4.w;
    if (tid < 256) {
      int kb = tid >> 4, nb = (tid & 15) * 4;
      float4 b4 = *(const float4*)(p.k_w + (size_t)(k0 + kb) * 512 + col0 + nb);
      sB[kb][nb + 0] = b4.x; sB[kb][nb + 1] = b4.y;
      sB[kb][nb + 2] = b4.z; sB[kb][nb + 3] = b4.w;
    }
    __syncthreads();
#pragma unroll
    for (int k = 0; k < 16; k++) {
      float ar[4], br[4];
#pragma unroll
      for (int i = 0; i < 4; i++) { ar[i] = sA[k][ty * 4 + i]; br[i] = sB[k][tx * 4 + i]; }
#pragma unroll
      for (int i = 0; i < 4; i++)
#pragma unroll
        for (int j = 0; j < 4; j++) acc[i][j] = fmaf(ar[i], br[j], acc[i][j]);
    }
  }
#pragma unroll
  for (int i = 0; i < 4; i++)
#pragma unroll
    for (int j = 0; j < 4; j++)
      p.hkeys[(size_t)(row0 + ty * 4 + i) * 512 + col0 + tx * 4 + j] = __float2half(acc[i][j]);
}

// ---------------- prep: repack weights + zero state/flags ----------------
__global__ __launch_bounds__(256) void k_repack(Params p) {
  const int gsz = gridDim.x * 256;
  const int t0 = blockIdx.x * 256 + threadIdx.x;
  for (int i = t0; i < 1280 * 512; i += gsz) {
    int r = i >> 9, u = i & 511;
    const float* src = (r < 768) ? p.attn_wi + (size_t)r * 1536 : p.attn_wh + (size_t)(r - 768) * 1536;
    __half2* d = (__half2*)(p.gw1T + ((size_t)i << 2));
    d[0] = __halves2half2(__float2half(src[u]), __float2half(src[512 + u]));
    d[1] = __halves2half2(__float2half(src[1024 + u]), __float2half(0.f));
  }
  for (int i = t0; i < 1536 * 512; i += gsz) {
    int r = i >> 9, u = i & 511;
    const float* src = (r < 1024) ? p.out_wi + (size_t)r * 1536 : p.out_wh + (size_t)(r - 1024) * 1536;
    __half2* d = (__half2*)(p.gw2T + ((size_t)i << 2));
    d[0] = __halves2half2(__float2half(src[u]), __float2half(src[512 + u]));
    d[1] = __halves2half2(__float2half(src[1024 + u]), __float2half(0.f));
  }
  for (int i = t0; i < 1024 * 128; i += gsz) {
    int k = i >> 7, m = i & 127;
    p.decT[(size_t)m * 1024 + k] = __float2half(p.dec_w[(size_t)k * 128 + m]);
  }
  for (int i = t0; i < 1024; i += gsz) p.gateh[i] = __float2half(p.gate_w[i]);
  for (int i = t0; i < 16384; i += gsz) p.locwh[i] = __float2half(p.loc_w[i]);
  for (int i = t0; i < 128 * 256; i += gsz) {
    int m = i >> 8, pc = i & 255;
    p.pre1T[(size_t)pc * 128 + m] = __float2half(p.pre_w1[(size_t)m * 256 + pc]);
  }
  for (int i = t0; i < 256 * 256; i += gsz) {
    int k = i >> 8, pc = i & 255;
    p.pre2T[(size_t)pc * 256 + k] = __float2half(p.pre_w2[(size_t)k * 256 + pc]);
  }
  for (int i = t0; i < 106496; i += gsz) p.stateZ[i] = 0.f;
  for (int i = t0; i < 16384; i += gsz) p.ctxacc[i] = 0.f;
  for (int i = t0; i < 16384; i += gsz) p.ctxacc2[i] = 0.f;
  for (int i = t0; i < 16384; i += gsz) p.qacc1[i] = 0.f;
  for (int i = t0; i < 16384; i += gsz) p.qacc2[i] = 0.f;
  // zdone / done2 / hAdone / done: 4 x 512 ints contiguous
  for (int i = t0; i < 2048; i += gsz) p.zdone[i] = 0;
  for (int i = t0; i < 12800; i += gsz) {
    int b = i / 400, t = i - b * 400;
    p.out_mask[i] = (t > p.mel_lens[b]) ? 1.f : 0.f;
  }
}

struct SMemMega {
  __half keysL[64 * 512];   // persistent P2 keys tile (64 KB)
  float ctxL[4][520];       // persistent ctx (row stagger: 520 % 32 = 8 banks)
  float hA2[4][520];        // persistent hA_next (staged in P2)
  float hOL[4][520];        // persistent hO carry (S6 pull -> next-step GRU2 hO-part)
  float decinL[4][264];     // persistent decin carry (S6 -> next-step P1f)
  float invZ[4];
  union {
    struct { float4 part4[16][64]; float hAslice[4][16]; } gr;
    struct { float locS[64][33]; float aw[94]; float ac[94];
             float qS[512]; float cpred[8][512]; float eS[64]; } s3;
    struct { float xh[4][1032]; float red[4][264]; float mel[4][132]; float p1[4][264]; } s6;
  } u;
};

// GRU partial accumulation over interleaved rows r = ks + 16*j, j in [j0,j1).
__device__ __forceinline__ void gchunk(const uint2* __restrict__ w,
                                       const float* __restrict__ x, int ks,
                                       int j0, int j1,
                                       float& a0, float& a1, float& a2) {
#pragma unroll 8
  for (int j = j0; j < j1; ++j) {
    uint2 wv = w[(size_t)j << 13];          // + j*16 rows * 512
    float xv = x[ks + (j << 4)];
    float2 f0 = cvt2(wv.x);
    float nf = cvt2(wv.y).x;
    a0 = fmaf(xv, f0.x, a0);
    a1 = fmaf(xv, f0.y, a1);
    a2 = fmaf(xv, nf, a2);
  }
}

__global__ __launch_bounds__(NTHR) void mega(Params p) {
  __shared__ SMemMega sm;
  const int blk = blockIdx.x, tid = threadIdx.x;
  const int ug = blk & 31, bg = blk >> 5, b0 = bg * 4;       // GRU identity
  const int bS = blk & 31, t8 = blk >> 5, t0g = t8 << 6;     // attention identity

  const int u_ = tid & 15, b2_ = (tid >> 4) & 3, ks_ = tid >> 6;
  const int uG_ = (ug << 4) + u_;
  const uint2* w1 = (const uint2*)p.gw1T + ((size_t)ks_ << 9) + uG_;
  const uint2* w2 = (const uint2*)p.gw2T + ((size_t)ks_ << 9) + uG_;

  // ---- one-time: load keys tile into LDS, zero persistent state ----
  {
    const uint4* src = (const uint4*)(p.hkeys + (((size_t)(bS << 9) + t0g) << 9));
    uint4* dst = (uint4*)sm.keysL;
    for (int i = tid; i < 4096; i += NTHR) dst[i] = src[i];
    for (int i = tid; i < 2048; i += NTHR) {
      sm.ctxL[i >> 9][i & 511] = 0.f;
      sm.hA2[i >> 9][i & 511] = 0.f;
      sm.hOL[i >> 9][i & 511] = 0.f;
    }
    for (int i = tid; i < 1024; i += NTHR) sm.decinL[i >> 8][i & 255] = 0.f;
  }
  __syncthreads();

  // GRU1 partial accumulators carried from P3 (prev step) into P1f (this step).
  float g1r = 0.f, g1z = 0.f, g1ni = 0.f, g1nh = 0.f;

#pragma clang loop unroll(disable)
  for (int step = 0; step < 400; step++) {
    const int par = step & 1;
    float* hA_next = p.hA + (par ^ 1) * 16384;
    float* hO_next = p.hO + (par ^ 1) * 16384;
    float* cCur = par ? p.ctxacc2 : p.ctxacc;
    float* cNxt = par ? p.ctxacc : p.ctxacc2;
    float* qCur = par ? p.qacc2 : p.qacc1;
    float* qNxt = par ? p.qacc1 : p.qacc2;

    // GRU2 partial accumulators for THIS step
    float r2 = 0.f, z2 = 0.f, ni2 = 0.f, nh2 = 0.f;

    // ======== P1f: finish GRU1 (decin rows, local) + hA + q-partial + GRU2 hO-part ========
    {
      gchunk(w1, &sm.decinL[b2_][0], ks_, 0, 16, g1r, g1z, g1ni);  // decin rows 0..255
      sm.u.gr.part4[ks_][(u_ << 2) + b2_] = make_float4(g1r, g1z, g1ni, g1nh);
      __syncthreads();
      if (tid < 64) {
        int uu = tid >> 2, bb2 = tid & 3;
        float4 s = make_float4(0.f, 0.f, 0.f, 0.f);
#pragma unroll
        for (int l = 0; l < 16; l++) {
          float4 v = sm.u.gr.part4[l][(uu << 2) + bb2];
          s.x += v.x; s.y += v.y; s.z += v.z; s.w += v.w;
        }
        int uGf = (ug << 4) + uu;
        float r = fast_sigmoid(s.x + p.attn_bi[uGf] + p.attn_bh[uGf]);
        float z = fast_sigmoid(s.y + p.attn_bi[512 + uGf] + p.attn_bh[512 + uGf]);
        float n = fast_tanh(s.z + p.attn_bi[1024 + uGf] + r * (s.w + p.attn_bh[1024 + uGf]));
        float hv = sm.hA2[bb2][uGf];             // hA_prev held locally
        float hnew = (1.f - z) * n + z * hv;
        sta(&hA_next[((b0 + bb2) << 9) + uGf], hnew);
        sm.u.gr.hAslice[bb2][uu] = hnew;
      }
      __syncthreads();
      // q-partial: this block's 16 k-rows of q = hA @ q_w (fp32 weights, coalesced)
      {
        int a = tid & 511, bh = tid >> 9;        // bh=0 -> batches 0,1 ; bh=1 -> 2,3
        const float* qw = p.q_w + ((size_t)(ug << 4)) * 512 + a;
        float s0 = 0.f, s1 = 0.f;
#pragma unroll
        for (int u = 0; u < 16; u++) {
          float w = qw[(size_t)u * 512];
          s0 = fmaf(sm.u.gr.hAslice[bh * 2][u], w, s0);
          s1 = fmaf(sm.u.gr.hAslice[bh * 2 + 1][u], w, s1);
        }
        atomicAdd(&qCur[((b0 + bh * 2) << 9) + a], s0);
        atomicAdd(&qCur[((b0 + bh * 2 + 1) << 9) + a], s1);
      }
      // release: every wave issued q-atomics (wave0 also hA stores); per-wave drain+publish
      if ((tid & 63) == 0) {
        asm volatile("s_waitcnt vmcnt(0)" ::: "memory");
        atomicAdd(&p.hAdone[(b0 + ((tid >> 6) & 3)) * 16], 0);  // touch nothing: see below
      }
      // publish 16 increments (one per wave) on the bg's shared progress counters:
      // use batch (wave&3) so each batch flag gets 4 incr/block -> 128/step total
      if ((tid & 63) == 0) {
        atomicAdd(&p.hAdone[(b0 + ((tid >> 6) & 3)) * 16], 1);
      }
      // GRU2 hO-part (rows 1024..1535) from local hOL
      gchunk(w2, &sm.hOL[b2_][0] - 1024, ks_, 64, 96, r2, z2, nh2);
    }

    // ======== P2: q read + conv + score + e + ctx partials + GRU2 hA-part ========
    {
      if (tid == 0) {
        while (ldai(&p.hAdone[bS * 16]) < 128 * (step + 1))
          __builtin_amdgcn_s_sleep(2);
      }
      __syncthreads();
      for (int j = tid; j < 94; j += NTHR) {
        int pp = t0g - 15 + j;
        bool ok = (unsigned)pp < 512u;
        sm.u.s3.aw[j] = ok ? lda(&p.attw[(bS << 9) + pp]) : 0.f;
        sm.u.s3.ac[j] = ok ? lda(&p.attcum[(bS << 9) + pp]) : 0.f;
      }
      if (t8 == 0) {
        for (int i = tid; i < 512; i += NTHR) {
          sta(&cNxt[(bS << 9) + i], 0.f);
          sta(&qNxt[(bS << 9) + i], 0.f);
        }
      }
      if (tid < 512) sm.u.s3.qS[tid] = lda(&qCur[(bS << 9) + tid]) + p.loc_b[tid];
      __syncthreads();
      const int tlen = p.text_lens[bS];
      for (int i = tid; i < 2048; i += NTHR) {
        int tt = i >> 5, f = i & 31;
        const float* w0 = p.conv_w + f * 62;
        float a = 0.f;
#pragma unroll
        for (int k = 0; k < 31; k++)
          a = fmaf(w0[k], sm.u.s3.aw[tt + k], fmaf(w0[31 + k], sm.u.s3.ac[tt + k], a));
        sm.u.s3.locS[tt][f] = a;
      }
      __syncthreads();
      const int lane = tid & 63, wv = tid >> 6;
      float acc[4][8];
      float4 qA = *(const float4*)&sm.u.s3.qS[lane * 8];
      float4 qB = *(const float4*)&sm.u.s3.qS[lane * 8 + 4];
#pragma unroll
      for (int j = 0; j < 4; j++) {
        int tL = wv * 4 + j;
        HU4 raw; raw.u = *(const uint4*)&sm.keysL[tL * 512 + lane * 8];
        float2 k0 = __half22float2(raw.h[0]), k1 = __half22float2(raw.h[1]);
        float2 k2 = __half22float2(raw.h[2]), k3 = __half22float2(raw.h[3]);
        acc[j][0] = qA.x + k0.x; acc[j][1] = qA.y + k0.y;
        acc[j][2] = qA.z + k1.x; acc[j][3] = qA.w + k1.y;
        acc[j][4] = qB.x + k2.x; acc[j][5] = qB.y + k2.y;
        acc[j][6] = qB.z + k3.x; acc[j][7] = qB.w + k3.y;
      }
#pragma unroll 4
      for (int f = 0; f < 32; f++) {
        HU4 rw; rw.u = *(const uint4*)(p.locwh + (size_t)f * 512 + lane * 8);
        float2 w0 = __half22float2(rw.h[0]), w1 = __half22float2(rw.h[1]);
        float2 w2v = __half22float2(rw.h[2]), w3 = __half22float2(rw.h[3]);
#pragma unroll
        for (int j = 0; j < 4; j++) {
          float lf = sm.u.s3.locS[wv * 4 + j][f];
          acc[j][0] = fmaf(lf, w0.x, acc[j][0]); acc[j][1] = fmaf(lf, w0.y, acc[j][1]);
          acc[j][2] = fmaf(lf, w1.x, acc[j][2]); acc[j][3] = fmaf(lf, w1.y, acc[j][3]);
          acc[j][4] = fmaf(lf, w2v.x, acc[j][4]); acc[j][5] = fmaf(lf, w2v.y, acc[j][5]);
          acc[j][6] = fmaf(lf, w3.x, acc[j][6]); acc[j][7] = fmaf(lf, w3.y, acc[j][7]);
        }
      }
      float4 sA = *(const float4*)(p.score_w + lane * 8);
      float4 sB = *(const float4*)(p.score_w + lane * 8 + 4);
      float sbias = p.score_b[0];
      float e_reg[4];
#pragma unroll
      for (int j = 0; j < 4; j++) {
        float pv = fast_tanh(acc[j][0]) * sA.x + fast_tanh(acc[j][1]) * sA.y +
                   fast_tanh(acc[j][2]) * sA.z + fast_tanh(acc[j][3]) * sA.w +
                   fast_tanh(acc[j][4]) * sB.x + fast_tanh(acc[j][5]) * sB.y +
                   fast_tanh(acc[j][6]) * sB.z + fast_tanh(acc[j][7]) * sB.w;
#pragma unroll
        for (int off = 32; off > 0; off >>= 1) pv += __shfl_xor(pv, off, 64);
        int t = t0g + wv * 4 + j;
        e_reg[j] = (t > tlen) ? 0.f : __expf(pv + sbias);
      }
      if (lane == 0) {
#pragma unroll
        for (int j = 0; j < 4; j++) sm.u.s3.eS[wv * 4 + j] = e_reg[j];
      }
      float cp[8] = {0.f, 0.f, 0.f, 0.f, 0.f, 0.f, 0.f, 0.f};
#pragma unroll
      for (int j = 0; j < 4; j++) {
        int tL = wv * 4 + j;
        HU4 raw; raw.u = *(const uint4*)&sm.keysL[tL * 512 + lane * 8];
        float2 k0 = __half22float2(raw.h[0]), k1 = __half22float2(raw.h[1]);
        float2 k2 = __half22float2(raw.h[2]), k3 = __half22float2(raw.h[3]);
        float e = e_reg[j];
        cp[0] = fmaf(e, k0.x, cp[0]); cp[1] = fmaf(e, k0.y, cp[1]);
        cp[2] = fmaf(e, k1.x, cp[2]); cp[3] = fmaf(e, k1.y, cp[3]);
        cp[4] = fmaf(e, k2.x, cp[4]); cp[5] = fmaf(e, k2.y, cp[5]);
        cp[6] = fmaf(e, k3.x, cp[6]); cp[7] = fmaf(e, k3.y, cp[7]);
      }
      __syncthreads();
      if (wv < 8) {
        float4* r0 = (float4*)&sm.u.s3.cpred[wv][lane * 8];
        r0[0] = make_float4(cp[0], cp[1], cp[2], cp[3]);
        r0[1] = make_float4(cp[4], cp[5], cp[6], cp[7]);
      }
      __syncthreads();
      if (wv >= 8) {
        float* r0 = &sm.u.s3.cpred[wv - 8][lane * 8];
#pragma unroll
        for (int i = 0; i < 8; i++) r0[i] += cp[i];
      }
      __syncthreads();
      if (tid < 512) {
        float s = 0.f;
#pragma unroll
        for (int j = 0; j < 8; j++) s += sm.u.s3.cpred[j][tid];
        atomicAdd(&cCur[(bS << 9) + tid], s);
      }
      if (tid < 64) {
        float e = sm.u.s3.eS[tid];
        sta(&p.ebuf[(bS << 9) + t0g + tid], e);
        float z = e;
#pragma unroll
        for (int off = 32; off > 0; off >>= 1) z += __shfl_xor(z, off, 64);
        if (tid == 0) sta(&p.zpart[bS * 8 + t8], z);
      }
      if (tid < 512 && (tid & 63) == 0) {
        asm volatile("s_waitcnt vmcnt(0)" ::: "memory");
        atomicAdd(&p.zdone[bS * 16], 1);
      }
      // ---- stage hA2 (own bg) + GRU2 hA-part ----
      if (tid < 4) {
        while (ldai(&p.hAdone[(b0 + tid) * 16]) < 128 * (step + 1))
          __builtin_amdgcn_s_sleep(2);
      }
      __syncthreads();
      for (int i = tid; i < 2048; i += NTHR)
        sm.hA2[i >> 9][i & 511] = lda(&hA_next[((b0 + (i >> 9)) << 9) + (i & 511)]);
      __syncthreads();
      gchunk(w2, &sm.hA2[b2_][0], ks_, 0, 32, r2, z2, ni2);   // rows 0..511
    }

    // ======== P3: ctx + GRU2 finish + GRU1-pre + replicated S6 ========
    {
      if (tid < 4) {
        while (ldai(&p.zdone[(b0 + tid) * 16]) < 64 * (step + 1))
          __builtin_amdgcn_s_sleep(2);
        float Z = 0.f;
#pragma unroll
        for (int j = 0; j < 8; j++) Z += lda(&p.zpart[(b0 + tid) * 8 + j]);
        sm.invZ[tid] = fast_rcp(Z);
      }
      __syncthreads();
      for (int i = tid; i < 2048; i += NTHR) {
        int b2 = i >> 9, a = i & 511;
        sm.ctxL[b2][a] = lda(&cCur[((b0 + b2) << 9) + a]) * sm.invZ[b2];
      }
      if (ug < 4 && tid < 512) {
        const int bb = b0 + ug;
        float v = lda(&p.ebuf[(bb << 9) + tid]) * sm.invZ[ug];
        sta(&p.attw[(bb << 9) + tid], v);
        float oc = lda(&p.attcum[(bb << 9) + tid]);
        sta(&p.attcum[(bb << 9) + tid], oc + v);
        ntst(&p.out_attn[(size_t)bb * 204800 + (size_t)step * 512 + tid], v);
      }
      __syncthreads();
      gchunk(w2, &sm.ctxL[b2_][0] - 512, ks_, 32, 64, r2, z2, ni2);  // ctx rows
      sm.u.gr.part4[ks_][(u_ << 2) + b2_] = make_float4(r2, z2, ni2, nh2);
      __syncthreads();
      if (tid < 64) {
        int uu = tid >> 2, bb2 = tid & 3;
        float4 s = make_float4(0.f, 0.f, 0.f, 0.f);
#pragma unroll
        for (int l = 0; l < 16; l++) {
          float4 v = sm.u.gr.part4[l][(uu << 2) + bb2];
          s.x += v.x; s.y += v.y; s.z += v.z; s.w += v.w;
        }
        int uGf = (ug << 4) + uu;
        float r = fast_sigmoid(s.x + p.out_bi[uGf] + p.out_bh[uGf]);
        float z = fast_sigmoid(s.y + p.out_bi[512 + uGf] + p.out_bh[512 + uGf]);
        float n = fast_tanh(s.z + p.out_bi[1024 + uGf] + r * (s.w + p.out_bh[1024 + uGf]));
        float hv = sm.hOL[bb2][uGf];
        sta(&hO_next[((b0 + bb2) << 9) + uGf], (1.f - z) * n + z * hv);
      }
      asm volatile("s_waitcnt vmcnt(0)" ::: "memory");
      if (tid < 4) atomicAdd(&p.done[(b0 + tid) * 16], 1);
      // ---- GRU1 pre-accumulation for NEXT step (hidden in the done-straggler window) ----
      g1r = 0.f; g1z = 0.f; g1ni = 0.f; g1nh = 0.f;
      if (step < 399) {
        gchunk(w1, &sm.ctxL[b2_][0] - 256, ks_, 16, 48, g1r, g1z, g1ni);
        gchunk(w1, &sm.hA2[b2_][0] - 768, ks_, 48, 80, g1r, g1z, g1nh);
      }
      // ---- replicated S6: all blocks, 4 batches in parallel (256 thr each) ----
      if (tid < 4) {
        while (ldai(&p.done[(b0 + tid) * 16]) < 32 * (step + 1))
          __builtin_amdgcn_s_sleep(2);
      }
      __syncthreads();
      for (int i = tid; i < 4096; i += NTHR) {
        int b = i >> 10, j = i & 1023;
        float v;
        if (j < 512) { v = lda(&hO_next[((b0 + b) << 9) + j]); sm.hOL[b][j] = v; }
        else v = sm.ctxL[b][j - 512];
        sm.u.s6.xh[b][j] = v;
      }
      __syncthreads();
      {
        int b = tid >> 8, t = tid & 255, m = t & 127, kh = t >> 7;
        const HU4* dp = (const HU4*)(p.decT + (size_t)m * 1024 + kh * 512);
        const float* xb = &sm.u.s6.xh[b][kh * 512];
        float a = 0.f;
#pragma unroll 8
        for (int it = 0; it < 64; it++) {
          HU4 raw = dp[it];
          int kb = it * 8;
#pragma unroll
          for (int h2 = 0; h2 < 4; h2++) {
            float2 w = __half22float2(raw.h[h2]);
            a = fmaf(xb[kb + h2 * 2], w.x, a);
            a = fmaf(xb[kb + h2 * 2 + 1], w.y, a);
          }
        }
        sm.u.s6.red[b][t] = a;
      }
      __syncthreads();
      if (tid < 512) {
        int b = tid >> 7, m = tid & 127;
        float mv = p.dec_b[m] + sm.u.s6.red[b][m] + sm.u.s6.red[b][m + 128];
        sm.u.s6.mel[b][m] = mv;
        if (ug < 4 && b == ug) {   // one writer block per batch for outputs
          int bb = b0 + b;
          bool masked = step > p.mel_lens[bb];
          ntst(&p.out_mel[(size_t)bb * 51200 + (size_t)step * 128 + m], masked ? 0.f : mv);
        }
      }
      __syncthreads();
      {
        int b = tid >> 8, t = tid & 255;
        float g = 0.f;
#pragma unroll
        for (int j = 0; j < 4; j++)
          g += sm.u.s6.xh[b][t + j * 256] * __half2float(p.gateh[t + j * 256]);
        sm.u.s6.red[b][t] = g;
      }
      __syncthreads();
      if (ug < 4 && tid < 256) {
        int b = tid >> 6, l = tid & 63;
        if (b == ug) {
          float g = sm.u.s6.red[b][l] + sm.u.s6.red[b][l + 64] +
                    sm.u.s6.red[b][l + 128] + sm.u.s6.red[b][l + 192];
#pragma unroll
          for (int off = 32; off > 0; off >>= 1) g += __shfl_xor(g, off, 64);
          if (l == 0) {
            int bb = b0 + b;
            bool masked = step > p.mel_lens[bb];
            ntst(&p.out_gate[bb * 400 + step], masked ? 1000.f : (g + p.gate_b[0]));
          }
        }
      }
      {
        int b = tid >> 8, pc = tid & 255;
        const HU4* wp = (const HU4*)(p.pre1T + (size_t)pc * 128);
        float a = 0.f;
#pragma unroll
        for (int it = 0; it < 16; it++) {
          HU4 raw = wp[it];
          int kb = it * 8;
#pragma unroll
          for (int h2 = 0; h2 < 4; h2++) {
            float2 w = __half22float2(raw.h[h2]);
            a = fmaf(sm.u.s6.mel[b][kb + h2 * 2], w.x, a);
            a = fmaf(sm.u.s6.mel[b][kb + h2 * 2 + 1], w.y, a);
          }
        }
        sm.u.s6.p1[b][pc] = fmaxf(a, 0.f);
      }
      __syncthreads();
      {
        int b = tid >> 8, pc = tid & 255;
        const HU4* wp = (const HU4*)(p.pre2T + (size_t)pc * 256);
        float a = 0.f;
#pragma unroll 8
        for (int it = 0; it < 32; it++) {
          HU4 raw = wp[it];
          int kb = it * 8;
#pragma unroll
          for (int h2 = 0; h2 < 4; h2++) {
            float2 w = __half22float2(raw.h[h2]);
            a = fmaf(sm.u.s6.p1[b][kb + h2 * 2], w.x, a);
            a = fmaf(sm.u.s6.p1[b][kb + h2 * 2 + 1], w.y, a);
          }
        }
        sm.decinL[b][pc] = fmaxf(a, 0.f);
      }
      __syncthreads();   // decinL ready; union handoff to next P1f
    }
  }
}

extern "C" void kernel_launch(void* const* d_in, const int* in_sizes, int n_in,
                              void* d_out, int out_size, void* d_ws, size_t ws_size,
                              hipStream_t stream) {
  Params p;
  p.enc       = (const float*)d_in[0];
  p.text_lens = (const int*)d_in[2];
  p.mel_lens  = (const int*)d_in[3];
  p.pre_w1    = (const float*)d_in[5];
  p.pre_w2    = (const float*)d_in[6];
  p.attn_wi   = (const float*)d_in[7];
  p.attn_wh   = (const float*)d_in[8];
  p.attn_bi   = (const float*)d_in[9];
  p.attn_bh   = (const float*)d_in[10];
  p.q_w       = (const float*)d_in[11];
  p.k_w       = (const float*)d_in[12];
  p.score_w   = (const float*)d_in[13];
  p.score_b   = (const float*)d_in[14];
  p.conv_w    = (const float*)d_in[15];
  p.loc_w     = (const float*)d_in[16];
  p.loc_b     = (const float*)d_in[17];
  p.out_wi    = (const float*)d_in[18];
  p.out_wh    = (const float*)d_in[19];
  p.out_bi    = (const float*)d_in[20];
  p.out_bh    = (const float*)d_in[21];
  p.dec_w     = (const float*)d_in[22];
  p.dec_b     = (const float*)d_in[23];
  p.gate_w    = (const float*)d_in[24];
  p.gate_b    = (const float*)d_in[25];

  float* ws = (float*)d_ws;
  p.hkeys  = (__half*)(ws);                    // 8,388,608 halfs
  p.gw1T   = (__half*)(ws + 4194304);
  p.gw2T   = (__half*)(ws + 5505024);
  p.decT   = (__half*)(ws + 7077888);
  p.pre1T  = (__half*)(ws + 7143424);
  p.pre2T  = (__half*)(ws + 7159808);
  p.gateh  = (__half*)(ws + 7192576);
  p.locwh  = (__half*)(ws + 7193088);
  p.qwT    = (__half*)(ws + 7201280);          // unused now
  p.hA     = ws + 7332352;
  p.hO     = ws + 7365120;
  p.attw   = ws + 7397888;
  p.attcum = ws + 7414272;
  p.decin  = ws + 7430656;                     // unused now (kept zeroed)
  p.stateZ = p.hA;                             // zero region: hA,hO,attw,attcum,decin = 106,496
  p.ebuf   = ws + 7438848;
  p.zpart  = ws + 7455232;
  p.ctxacc = ws + 7455488;                     // 16384
  p.ctxacc2 = ws + 7472416;                    // 16384
  p.zdone  = (int*)(ws + 7488800);             // 512 ints
  p.done2  = (int*)(ws + 7489312);             // 512 ints (unused)
  p.hAdone = (int*)(ws + 7489824);             // 512 ints
  p.done   = (int*)(ws + 7490336);             // 512 ints
  p.qacc1  = ws + 7490848;                     // 16384
  p.qacc2  = ws + 7507232;                     // 16384
  float* out = (float*)d_out;
  p.out_mel  = out;
  p.out_gate = out + 1638400;
  p.out_attn = out + 1651200;
  p.out_mask = out + 8204800;

  k_repack<<<2048, 256, 0, stream>>>(p);
  k_keys<<<dim3(128, 8), 512, 0, stream>>>(p);
  void* args[] = { (void*)&p };
  hipLaunchCooperativeKernel((const void*)mega, dim3(NBLK), dim3(NTHR), args, 0, stream);
}

// Round 7
// 53326.575 us; speedup vs baseline: 1.0924x; 1.0924x over previous
//
#include <hip/hip_runtime.h>
#include <hip/hip_fp16.h>
#include <math.h>

#define NBLK 256
#define NTHR 1024

__device__ __forceinline__ float fast_rcp(float x) {
#if __has_builtin(__builtin_amdgcn_rcpf)
  return __builtin_amdgcn_rcpf(x);
#else
  return 1.f / x;
#endif
}
__device__ __forceinline__ float fast_sigmoid(float x) { return fast_rcp(1.f + __expf(-x)); }
__device__ __forceinline__ float fast_tanh(float x) { return 1.f - 2.f * fast_rcp(1.f + __expf(2.f * x)); }

union HU2 { unsigned int u; __half2 h; };
union HU4 { uint4 u; __half2 h[4]; };
__device__ __forceinline__ float2 cvt2(unsigned int u) { HU2 t; t.u = u; return __half22float2(t.h); }

__device__ __forceinline__ void sta(float* p, float v) {
  __hip_atomic_store(p, v, __ATOMIC_RELAXED, __HIP_MEMORY_SCOPE_AGENT);
}
__device__ __forceinline__ float lda(const float* p) {
  return __hip_atomic_load(p, __ATOMIC_RELAXED, __HIP_MEMORY_SCOPE_AGENT);
}
__device__ __forceinline__ int ldai(const int* p) {
  return __hip_atomic_load(p, __ATOMIC_RELAXED, __HIP_MEMORY_SCOPE_AGENT);
}
__device__ __forceinline__ void ntst(float* p, float v) { __builtin_nontemporal_store(v, p); }

struct Params {
  const float *enc, *pre_w1, *pre_w2, *attn_bi, *attn_bh;
  const float *q_w, *k_w, *score_w, *score_b, *conv_w, *loc_w, *loc_b;
  const float *out_bi, *out_bh, *dec_b, *gate_b;
  const float *attn_wi, *attn_wh, *out_wi, *out_wh, *dec_w, *gate_w;
  const int *text_lens, *mel_lens;
  __half *hkeys, *gw1T, *gw2T, *pre1T, *pre2T, *locwh;
  float *hA, *hO, *attw, *attcum, *decin, *ebuf, *zpart, *ctxacc, *ctxacc2, *stateZ;
  float *qpart, *melpart, *gatepart;
  int *done, *zdone, *done2, *hAdone, *initbar;
  float *out_mel, *out_gate, *out_attn, *out_mask;
};

// ---------------- prep: keys GEMM (fp16 out) ----------------
__global__ __launch_bounds__(512) void k_keys(Params p) {
  __shared__ float sA[16][132];
  __shared__ float sB[16][68];
  int tid = threadIdx.x;
  int row0 = blockIdx.x * 128, col0 = blockIdx.y * 64;
  float acc[4][4] = {};
  int r = tid >> 2, kq = tid & 3;
  int tx = tid & 15, ty = tid >> 4;
  for (int k0 = 0; k0 < 1024; k0 += 16) {
    __syncthreads();
    float4 a4 = *(const float4*)(p.enc + (size_t)(row0 + r) * 1024 + k0 + kq * 4);
    sA[kq * 4 + 0][r] = a4.x; sA[kq * 4 + 1][r] = a4.y;
    sA[kq * 4 + 2][r] = a4.z; sA[kq * 4 + 3][r] = a4.w;
    if (tid < 256) {
      int kb = tid >> 4, nb = (tid & 15) * 4;
      float4 b4 = *(const float4*)(p.k_w + (size_t)(k0 + kb) * 512 + col0 + nb);
      sB[kb][nb + 0] = b4.x; sB[kb][nb + 1] = b4.y;
      sB[kb][nb + 2] = b4.z; sB[kb][nb + 3] = b4.w;
    }
    __syncthreads();
#pragma unroll
    for (int k = 0; k < 16; k++) {
      float ar[4], br[4];
#pragma unroll
      for (int i = 0; i < 4; i++) { ar[i] = sA[k][ty * 4 + i]; br[i] = sB[k][tx * 4 + i]; }
#pragma unroll
      for (int i = 0; i < 4; i++)
#pragma unroll
        for (int j = 0; j < 4; j++) acc[i][j] = fmaf(ar[i], br[j], acc[i][j]);
    }
  }
#pragma unroll
  for (int i = 0; i < 4; i++)
#pragma unroll
    for (int j = 0; j < 4; j++)
      p.hkeys[(size_t)(row0 + ty * 4 + i) * 512 + col0 + tx * 4 + j] = __float2half(acc[i][j]);
}

// ---------------- prep: repack weights + zero state/flags ----------------
__global__ __launch_bounds__(256) void k_repack(Params p) {
  const int gsz = gridDim.x * 256;
  const int t0 = blockIdx.x * 256 + threadIdx.x;
  for (int i = t0; i < 1280 * 512; i += gsz) {
    int r = i >> 9, u = i & 511;
    const float* src = (r < 768) ? p.attn_wi + (size_t)r * 1536 : p.attn_wh + (size_t)(r - 768) * 1536;
    __half2* d = (__half2*)(p.gw1T + ((size_t)i << 2));
    d[0] = __halves2half2(__float2half(src[u]), __float2half(src[512 + u]));
    d[1] = __halves2half2(__float2half(src[1024 + u]), __float2half(0.f));
  }
  for (int i = t0; i < 1536 * 512; i += gsz) {
    int r = i >> 9, u = i & 511;
    const float* src = (r < 1024) ? p.out_wi + (size_t)r * 1536 : p.out_wh + (size_t)(r - 1024) * 1536;
    __half2* d = (__half2*)(p.gw2T + ((size_t)i << 2));
    d[0] = __halves2half2(__float2half(src[u]), __float2half(src[512 + u]));
    d[1] = __halves2half2(__float2half(src[1024 + u]), __float2half(0.f));
  }
  for (int i = t0; i < 16384; i += gsz) p.locwh[i] = __float2half(p.loc_w[i]);
  for (int i = t0; i < 128 * 256; i += gsz) {
    int m = i >> 8, pc = i & 255;
    p.pre1T[(size_t)pc * 128 + m] = __float2half(p.pre_w1[(size_t)m * 256 + pc]);
  }
  for (int i = t0; i < 256 * 256; i += gsz) {
    int k = i >> 8, pc = i & 255;
    p.pre2T[(size_t)pc * 256 + k] = __float2half(p.pre_w2[(size_t)k * 256 + pc]);
  }
  for (int i = t0; i < 106496; i += gsz) p.stateZ[i] = 0.f;
  for (int i = t0; i < 16384; i += gsz) p.ctxacc[i] = 0.f;
  for (int i = t0; i < 16384; i += gsz) p.ctxacc2[i] = 0.f;
  // zdone-based flag region: 2048 ints (zdone/done2/hAdone/done per-bg + initbar)
  for (int i = t0; i < 2048; i += gsz) p.zdone[i] = 0;
  for (int i = t0; i < 12800; i += gsz) {
    int b = i / 400, t = i - b * 400;
    p.out_mask[i] = (t > p.mel_lens[b]) ? 1.f : 0.f;
  }
}

struct SMemMega {
  __half keysL[64 * 512];   // persistent P2 keys tile (64 KB)
  float ctxL[4][520];       // persistent ctx (row stagger)
  float hA2[4][520];        // persistent hA_next (staged in P2 tail)
  float hO2[4][520];        // persistent hO_prev (staged in P1f)
  float invZ[4];
  union {
    struct { float x[4][264]; float4 part4[16][64];
             float hAslice[4][16]; float hOslice[4][16]; } gr;
    struct { float locS[64][33]; float aw[94]; float ac[94];
             float qS[512]; float cpred[8][512]; float eS[64]; } s3;
    struct { float red[1024]; float mel[132]; float p1[264]; } s6;
  } u;
};

// GRU partial accumulation over interleaved rows r = ks + 16*j, j in [j0,j1).
__device__ __forceinline__ void gchunk(const uint2* __restrict__ w,
                                       const float* __restrict__ x, int ks,
                                       int j0, int j1,
                                       float& a0, float& a1, float& a2) {
#pragma unroll 8
  for (int j = j0; j < j1; ++j) {
    uint2 wv = w[(size_t)j << 13];          // + j*16 rows * 512
    float xv = x[ks + (j << 4)];
    float2 f0 = cvt2(wv.x);
    float nf = cvt2(wv.y).x;
    a0 = fmaf(xv, f0.x, a0);
    a1 = fmaf(xv, f0.y, a1);
    a2 = fmaf(xv, nf, a2);
  }
}

__global__ __launch_bounds__(NTHR) void mega(Params p) {
  __shared__ SMemMega sm;
  const int blk = blockIdx.x, tid = threadIdx.x;
  const int ug = blk & 31, bg = blk >> 5, b0 = bg * 4;       // GRU identity
  const int bS = blk & 31, t8 = blk >> 5, t0g = t8 << 6;     // attention identity
  const int bgS = bS >> 2;                                   // bg that owns batch bS

  const int u_ = tid & 15, b2_ = (tid >> 4) & 3, ks_ = tid >> 6;
  const int uG_ = (ug << 4) + u_;
  const uint2* w1 = (const uint2*)p.gw1T + ((size_t)ks_ << 9) + uG_;
  const uint2* w2 = (const uint2*)p.gw2T + ((size_t)ks_ << 9) + uG_;

  // ---- one-time: load keys tile into LDS, zero persistent LDS ----
  {
    const uint4* src = (const uint4*)(p.hkeys + (((size_t)(bS << 9) + t0g) << 9));
    uint4* dst = (uint4*)sm.keysL;
    for (int i = tid; i < 4096; i += NTHR) dst[i] = src[i];
    for (int i = tid; i < 2048; i += NTHR) {
      sm.ctxL[i >> 9][i & 511] = 0.f;
      sm.hA2[i >> 9][i & 511] = 0.f;
      sm.hO2[i >> 9][i & 511] = 0.f;
    }
  }
  __syncthreads();
  // one-time grid barrier: hkeys region is reused as qpart/melpart after this
  if (tid == 0) {
    atomicAdd(p.initbar, 1);
    while (ldai(p.initbar) < NBLK) __builtin_amdgcn_s_sleep(2);
  }
  __syncthreads();

  // GRU1 partial accumulators carried from P3 (prev step) into P1f (this step).
  float g1r = 0.f, g1z = 0.f, g1ni = 0.f, g1nh = 0.f;

#pragma clang loop unroll(disable)
  for (int step = 0; step < 400; step++) {
    const int par = step & 1;
    float* hA_prev = p.hA + par * 16384;
    float* hA_next = p.hA + (par ^ 1) * 16384;
    float* hO_prev = p.hO + par * 16384;
    float* hO_next = p.hO + (par ^ 1) * 16384;
    float* cCur = par ? p.ctxacc2 : p.ctxacc;
    float* cNxt = par ? p.ctxacc : p.ctxacc2;

    // GRU2 partial accumulators for THIS step
    float r2 = 0.f, z2 = 0.f, ni2 = 0.f, nh2 = 0.f;

    // ======== P1f: GRU1 finish (decin rows) + hA + q-partials + GRU2 hO-part ========
    {
      if (step > 0) {
        if (tid == 0) {
          while (ldai(&p.done2[bg * 16]) < 16 * step)
            __builtin_amdgcn_s_sleep(2);
        }
        __syncthreads();
      }
      for (int i = tid; i < 1024; i += NTHR)
        sm.u.gr.x[i >> 8][i & 255] = lda(&p.decin[((b0 + (i >> 8)) << 8) + (i & 255)]);
      for (int i = tid; i < 2048; i += NTHR)
        sm.hO2[i >> 9][i & 511] = lda(&hO_prev[((b0 + (i >> 9)) << 9) + (i & 511)]);
      __syncthreads();
      gchunk(w1, &sm.u.gr.x[b2_][0], ks_, 0, 16, g1r, g1z, g1ni);  // decin rows 0..255
      sm.u.gr.part4[ks_][(u_ << 2) + b2_] = make_float4(g1r, g1z, g1ni, g1nh);
      __syncthreads();
      if (tid < 64) {
        int uu = tid >> 2, bb2 = tid & 3;
        float4 s = make_float4(0.f, 0.f, 0.f, 0.f);
#pragma unroll
        for (int l = 0; l < 16; l++) {
          float4 v = sm.u.gr.part4[l][(uu << 2) + bb2];
          s.x += v.x; s.y += v.y; s.z += v.z; s.w += v.w;
        }
        int uGf = (ug << 4) + uu;
        float r = fast_sigmoid(s.x + p.attn_bi[uGf] + p.attn_bh[uGf]);
        float z = fast_sigmoid(s.y + p.attn_bi[512 + uGf] + p.attn_bh[512 + uGf]);
        float n = fast_tanh(s.z + p.attn_bi[1024 + uGf] + r * (s.w + p.attn_bh[1024 + uGf]));
        float hv = lda(&hA_prev[((b0 + bb2) << 9) + uGf]);
        float hnew = (1.f - z) * n + z * hv;
        sta(&hA_next[((b0 + bb2) << 9) + uGf], hnew);
        sm.u.gr.hAslice[bb2][uu] = hnew;
      }
      __syncthreads();
      // q-partials: private slots, no atomics. thread: (a, 2 batches), 16 MACs each.
      {
        int a = tid & 511, bh = tid >> 9;
        const float* qw = p.q_w + ((size_t)(ug << 4)) * 512 + a;
        float s0 = 0.f, s1 = 0.f;
#pragma unroll
        for (int u = 0; u < 16; u++) {
          float w = qw[(size_t)u * 512];
          s0 = fmaf(sm.u.gr.hAslice[bh * 2][u], w, s0);
          s1 = fmaf(sm.u.gr.hAslice[bh * 2 + 1][u], w, s1);
        }
        int base = ((((b0 + bh * 2) << 5) | ug) << 9) + a;
        sta(&p.qpart[base], s0);
        sta(&p.qpart[base + (1 << 14)], s1);     // next batch slot (+32*512)
      }
      // per-wave drain + publish (per-bg counter; 16 waves x 32 blocks = 512/step)
      if ((tid & 63) == 0) {
        asm volatile("s_waitcnt vmcnt(0)" ::: "memory");
        atomicAdd(&p.hAdone[bg * 16], 1);
      }
      // GRU2 hO-part (rows 1024..1535) from local hO2
      gchunk(w2, &sm.hO2[b2_][0] - 1024, ks_, 64, 96, r2, z2, nh2);
    }

    // ======== P2: conv (pre-wait) + q reduce + score + e + ctx partials + hA-part ========
    {
      __syncthreads();   // union gr -> s3 transition
      // stage aw/ac + zero cNxt BEFORE the wait (only depend on step-1 state)
      for (int j = tid; j < 94; j += NTHR) {
        int pp = t0g - 15 + j;
        bool ok = (unsigned)pp < 512u;
        sm.u.s3.aw[j] = ok ? lda(&p.attw[(bS << 9) + pp]) : 0.f;
        sm.u.s3.ac[j] = ok ? lda(&p.attcum[(bS << 9) + pp]) : 0.f;
      }
      if (t8 == 0) {
        for (int i = tid; i < 512; i += NTHR) sta(&cNxt[(bS << 9) + i], 0.f);
      }
      __syncthreads();
      const int tlen = p.text_lens[bS];
      for (int i = tid; i < 2048; i += NTHR) {
        int tt = i >> 5, f = i & 31;
        const float* w0 = p.conv_w + f * 62;
        float a = 0.f;
#pragma unroll
        for (int k = 0; k < 31; k++)
          a = fmaf(w0[k], sm.u.s3.aw[tt + k], fmaf(w0[31 + k], sm.u.s3.ac[tt + k], a));
        sm.u.s3.locS[tt][f] = a;
      }
      if (tid == 0) {
        while (ldai(&p.hAdone[bgS * 16]) < 512 * (step + 1))
          __builtin_amdgcn_s_sleep(2);
      }
      __syncthreads();
      // q reduce: 32 slots -> qS  (2 threads per a, 16 loads each)
      {
        int a = tid & 511, h = tid >> 9;
        const float* qp = p.qpart + (((size_t)(bS << 5) + (h << 4)) << 9) + a;
        float s = 0.f;
#pragma unroll
        for (int g = 0; g < 16; g++) s += lda(qp + ((size_t)g << 9));
        sm.u.s3.cpred[h][a] = s;
      }
      __syncthreads();
      if (tid < 512)
        sm.u.s3.qS[tid] = sm.u.s3.cpred[0][tid] + sm.u.s3.cpred[1][tid] + p.loc_b[tid];
      __syncthreads();
      const int lane = tid & 63, wv = tid >> 6;
      float acc[4][8];
      float4 qA = *(const float4*)&sm.u.s3.qS[lane * 8];
      float4 qB = *(const float4*)&sm.u.s3.qS[lane * 8 + 4];
#pragma unroll
      for (int j = 0; j < 4; j++) {
        int tL = wv * 4 + j;
        HU4 raw; raw.u = *(const uint4*)&sm.keysL[tL * 512 + lane * 8];
        float2 k0 = __half22float2(raw.h[0]), k1 = __half22float2(raw.h[1]);
        float2 k2 = __half22float2(raw.h[2]), k3 = __half22float2(raw.h[3]);
        acc[j][0] = qA.x + k0.x; acc[j][1] = qA.y + k0.y;
        acc[j][2] = qA.z + k1.x; acc[j][3] = qA.w + k1.y;
        acc[j][4] = qB.x + k2.x; acc[j][5] = qB.y + k2.y;
        acc[j][6] = qB.z + k3.x; acc[j][7] = qB.w + k3.y;
      }
#pragma unroll 4
      for (int f = 0; f < 32; f++) {
        HU4 rw; rw.u = *(const uint4*)(p.locwh + (size_t)f * 512 + lane * 8);
        float2 w0 = __half22float2(rw.h[0]), w1 = __half22float2(rw.h[1]);
        float2 w2v = __half22float2(rw.h[2]), w3 = __half22float2(rw.h[3]);
#pragma unroll
        for (int j = 0; j < 4; j++) {
          float lf = sm.u.s3.locS[wv * 4 + j][f];
          acc[j][0] = fmaf(lf, w0.x, acc[j][0]); acc[j][1] = fmaf(lf, w0.y, acc[j][1]);
          acc[j][2] = fmaf(lf, w1.x, acc[j][2]); acc[j][3] = fmaf(lf, w1.y, acc[j][3]);
          acc[j][4] = fmaf(lf, w2v.x, acc[j][4]); acc[j][5] = fmaf(lf, w2v.y, acc[j][5]);
          acc[j][6] = fmaf(lf, w3.x, acc[j][6]); acc[j][7] = fmaf(lf, w3.y, acc[j][7]);
        }
      }
      float4 sA = *(const float4*)(p.score_w + lane * 8);
      float4 sB = *(const float4*)(p.score_w + lane * 8 + 4);
      float sbias = p.score_b[0];
      float e_reg[4];
#pragma unroll
      for (int j = 0; j < 4; j++) {
        float pv = fast_tanh(acc[j][0]) * sA.x + fast_tanh(acc[j][1]) * sA.y +
                   fast_tanh(acc[j][2]) * sA.z + fast_tanh(acc[j][3]) * sA.w +
                   fast_tanh(acc[j][4]) * sB.x + fast_tanh(acc[j][5]) * sB.y +
                   fast_tanh(acc[j][6]) * sB.z + fast_tanh(acc[j][7]) * sB.w;
#pragma unroll
        for (int off = 32; off > 0; off >>= 1) pv += __shfl_xor(pv, off, 64);
        int t = t0g + wv * 4 + j;
        e_reg[j] = (t > tlen) ? 0.f : __expf(pv + sbias);
      }
      if (lane == 0) {
#pragma unroll
        for (int j = 0; j < 4; j++) sm.u.s3.eS[wv * 4 + j] = e_reg[j];
      }
      float cp[8] = {0.f, 0.f, 0.f, 0.f, 0.f, 0.f, 0.f, 0.f};
#pragma unroll
      for (int j = 0; j < 4; j++) {
        int tL = wv * 4 + j;
        HU4 raw; raw.u = *(const uint4*)&sm.keysL[tL * 512 + lane * 8];
        float2 k0 = __half22float2(raw.h[0]), k1 = __half22float2(raw.h[1]);
        float2 k2 = __half22float2(raw.h[2]), k3 = __half22float2(raw.h[3]);
        float e = e_reg[j];
        cp[0] = fmaf(e, k0.x, cp[0]); cp[1] = fmaf(e, k0.y, cp[1]);
        cp[2] = fmaf(e, k1.x, cp[2]); cp[3] = fmaf(e, k1.y, cp[3]);
        cp[4] = fmaf(e, k2.x, cp[4]); cp[5] = fmaf(e, k2.y, cp[5]);
        cp[6] = fmaf(e, k3.x, cp[6]); cp[7] = fmaf(e, k3.y, cp[7]);
      }
      __syncthreads();
      if (wv < 8) {
        float4* r0 = (float4*)&sm.u.s3.cpred[wv][lane * 8];
        r0[0] = make_float4(cp[0], cp[1], cp[2], cp[3]);
        r0[1] = make_float4(cp[4], cp[5], cp[6], cp[7]);
      }
      __syncthreads();
      if (wv >= 8) {
        float* r0 = &sm.u.s3.cpred[wv - 8][lane * 8];
#pragma unroll
        for (int i = 0; i < 8; i++) r0[i] += cp[i];
      }
      __syncthreads();
      if (tid < 512) {
        float s = 0.f;
#pragma unroll
        for (int j = 0; j < 8; j++) s += sm.u.s3.cpred[j][tid];
        atomicAdd(&cCur[(bS << 9) + tid], s);
      }
      if (tid < 64) {
        float e = sm.u.s3.eS[tid];
        sta(&p.ebuf[(bS << 9) + t0g + tid], e);
        float z = e;
#pragma unroll
        for (int off = 32; off > 0; off >>= 1) z += __shfl_xor(z, off, 64);
        if (tid == 0) sta(&p.zpart[bS * 8 + t8], z);
      }
      // per-wave drain + publish to per-bg zdone (waves 0..7 did all global stores)
      if (tid < 512 && (tid & 63) == 0) {
        asm volatile("s_waitcnt vmcnt(0)" ::: "memory");
        atomicAdd(&p.zdone[bgS * 16], 1);
      }
      // ---- stage hA2 (own bg) + GRU2 hA-part ----
      if (tid == 0) {
        while (ldai(&p.hAdone[bg * 16]) < 512 * (step + 1))
          __builtin_amdgcn_s_sleep(2);
      }
      __syncthreads();
      for (int i = tid; i < 2048; i += NTHR)
        sm.hA2[i >> 9][i & 511] = lda(&hA_next[((b0 + (i >> 9)) << 9) + (i & 511)]);
      __syncthreads();
      gchunk(w2, &sm.hA2[b2_][0], ks_, 0, 32, r2, z2, ni2);   // rows 0..511
    }

    // ======== P3: ctx + GRU2 finish + dec/gate partials + GRU1-pre + S6 ========
    {
      if (tid == 0) {
        while (ldai(&p.zdone[bg * 16]) < 256 * (step + 1))
          __builtin_amdgcn_s_sleep(2);
      }
      __syncthreads();
      if (tid < 4) {
        float Z = 0.f;
#pragma unroll
        for (int j = 0; j < 8; j++) Z += lda(&p.zpart[(b0 + tid) * 8 + j]);
        sm.invZ[tid] = fast_rcp(Z);
      }
      __syncthreads();
      for (int i = tid; i < 2048; i += NTHR) {
        int b2 = i >> 9, a = i & 511;
        sm.ctxL[b2][a] = lda(&cCur[((b0 + b2) << 9) + a]) * sm.invZ[b2];
      }
      if (ug < 4 && tid < 512) {
        const int bb = b0 + ug;
        float v = lda(&p.ebuf[(bb << 9) + tid]) * sm.invZ[ug];
        sta(&p.attw[(bb << 9) + tid], v);
        float oc = lda(&p.attcum[(bb << 9) + tid]);
        sta(&p.attcum[(bb << 9) + tid], oc + v);
        ntst(&p.out_attn[(size_t)bb * 204800 + (size_t)step * 512 + tid], v);
      }
      __syncthreads();
      gchunk(w2, &sm.ctxL[b2_][0] - 512, ks_, 32, 64, r2, z2, ni2);  // ctx rows
      sm.u.gr.part4[ks_][(u_ << 2) + b2_] = make_float4(r2, z2, ni2, nh2);
      __syncthreads();
      if (tid < 64) {
        int uu = tid >> 2, bb2 = tid & 3;
        float4 s = make_float4(0.f, 0.f, 0.f, 0.f);
#pragma unroll
        for (int l = 0; l < 16; l++) {
          float4 v = sm.u.gr.part4[l][(uu << 2) + bb2];
          s.x += v.x; s.y += v.y; s.z += v.z; s.w += v.w;
        }
        int uGf = (ug << 4) + uu;
        float r = fast_sigmoid(s.x + p.out_bi[uGf] + p.out_bh[uGf]);
        float z = fast_sigmoid(s.y + p.out_bi[512 + uGf] + p.out_bh[512 + uGf]);
        float n = fast_tanh(s.z + p.out_bi[1024 + uGf] + r * (s.w + p.out_bh[1024 + uGf]));
        float hv = sm.hO2[bb2][uGf];
        float hnew = (1.f - z) * n + z * hv;
        sta(&hO_next[((b0 + bb2) << 9) + uGf], hnew);
        sm.u.gr.hOslice[bb2][uu] = hnew;
      }
      __syncthreads();
      // dec/gate partials from own 16 hO rows + own 16 ctx rows (fp32 weights)
      if (tid < 512) {
        int b = tid >> 7, m = tid & 127;
        const float* dw = p.dec_w + ((size_t)(ug << 4)) * 128 + m;
        const float* dw2 = p.dec_w + ((size_t)(512 + (ug << 4))) * 128 + m;
        float a = 0.f;
#pragma unroll
        for (int u = 0; u < 16; u++) {
          a = fmaf(sm.u.gr.hOslice[b][u], dw[(size_t)u * 128], a);
          a = fmaf(sm.ctxL[b][(ug << 4) + u], dw2[(size_t)u * 128], a);
        }
        sta(&p.melpart[((((b0 + b) << 5) | ug) << 7) + m], a);
        if (m == 0) {
          const float* gw = p.gate_w + (ug << 4);
          float g = 0.f;
#pragma unroll
          for (int u = 0; u < 16; u++) {
            g = fmaf(sm.u.gr.hOslice[b][u], gw[u], g);
            g = fmaf(sm.ctxL[b][(ug << 4) + u], gw[512 + u], g);
          }
          sta(&p.gatepart[((b0 + b) << 5) | ug], g);
        }
      }
      // per-wave drain + publish (per-bg done; 16 waves x 32 blocks = 512/step)
      if ((tid & 63) == 0) {
        asm volatile("s_waitcnt vmcnt(0)" ::: "memory");
        atomicAdd(&p.done[bg * 16], 1);
      }
      // ---- GRU1 pre-accumulation for NEXT step (overlaps the done-straggler window) ----
      g1r = 0.f; g1z = 0.f; g1ni = 0.f; g1nh = 0.f;
      if (step < 399) {
        gchunk(w1, &sm.ctxL[b2_][0] - 256, ks_, 16, 48, g1r, g1z, g1ni);
        gchunk(w1, &sm.hA2[b2_][0] - 768, ks_, 48, 80, g1r, g1z, g1nh);
      }
      // ---- S6 (ug<4, own batch): reduce partials + prenet ----
      if (ug < 4) {
        const int bb = b0 + ug;
        if (tid == 0) {
          while (ldai(&p.done[bg * 16]) < 512 * (step + 1))
            __builtin_amdgcn_s_sleep(2);
        }
        __syncthreads();
        bool masked = step > p.mel_lens[bb];
        if (tid < 128) {
          const float* mp = p.melpart + (((size_t)(bb << 5)) << 7) + tid;
          float mv = p.dec_b[tid];
#pragma unroll
          for (int g = 0; g < 32; g++) mv += lda(mp + (g << 7));
          sm.u.s6.mel[tid] = mv;
          ntst(&p.out_mel[(size_t)bb * 51200 + (size_t)step * 128 + tid], masked ? 0.f : mv);
        }
        if (tid >= 128 && tid < 192) {
          int l = tid & 63;
          float g = (l < 32) ? lda(&p.gatepart[(bb << 5) + l]) : 0.f;
#pragma unroll
          for (int off = 16; off > 0; off >>= 1) g += __shfl_xor(g, off, 64);
          if (l == 0)
            ntst(&p.out_gate[bb * 400 + step], masked ? 1000.f : (g + p.gate_b[0]));
        }
        __syncthreads();
        {
          int pc = tid & 255, ks = tid >> 8;
          const HU4* wp = (const HU4*)(p.pre1T + (size_t)pc * 128 + ks * 32);
          float a = 0.f;
#pragma unroll
          for (int it = 0; it < 4; it++) {
            HU4 raw = wp[it];
            int kb = ks * 32 + it * 8;
#pragma unroll
            for (int h2 = 0; h2 < 4; h2++) {
              float2 w = __half22float2(raw.h[h2]);
              a = fmaf(sm.u.s6.mel[kb + h2 * 2], w.x, a);
              a = fmaf(sm.u.s6.mel[kb + h2 * 2 + 1], w.y, a);
            }
          }
          sm.u.s6.red[tid] = a;
        }
        __syncthreads();
        if (tid < 256) {
          float a = sm.u.s6.red[tid] + sm.u.s6.red[tid + 256] +
                    sm.u.s6.red[tid + 512] + sm.u.s6.red[tid + 768];
          sm.u.s6.p1[tid] = fmaxf(a, 0.f);
        }
        __syncthreads();
        {
          int pc = tid & 255, ks = tid >> 8;
          const HU4* wp = (const HU4*)(p.pre2T + (size_t)pc * 256 + ks * 64);
          float a = 0.f;
#pragma unroll
          for (int it = 0; it < 8; it++) {
            HU4 raw = wp[it];
            int kb = ks * 64 + it * 8;
#pragma unroll
            for (int h2 = 0; h2 < 4; h2++) {
              float2 w = __half22float2(raw.h[h2]);
              a = fmaf(sm.u.s6.p1[kb + h2 * 2], w.x, a);
              a = fmaf(sm.u.s6.p1[kb + h2 * 2 + 1], w.y, a);
            }
          }
          sm.u.s6.red[tid] = a;
        }
        __syncthreads();
        if (tid < 256) {
          float a = sm.u.s6.red[tid] + sm.u.s6.red[tid + 256] +
                    sm.u.s6.red[tid + 512] + sm.u.s6.red[tid + 768];
          sta(&p.decin[(bb << 8) + tid], fmaxf(a, 0.f));
        }
        if (tid < 256 && (tid & 63) == 0) {
          asm volatile("s_waitcnt vmcnt(0)" ::: "memory");
          atomicAdd(&p.done2[bg * 16], 1);
        }
      }
    }
  }
}

extern "C" void kernel_launch(void* const* d_in, const int* in_sizes, int n_in,
                              void* d_out, int out_size, void* d_ws, size_t ws_size,
                              hipStream_t stream) {
  Params p;
  p.enc       = (const float*)d_in[0];
  p.text_lens = (const int*)d_in[2];
  p.mel_lens  = (const int*)d_in[3];
  p.pre_w1    = (const float*)d_in[5];
  p.pre_w2    = (const float*)d_in[6];
  p.attn_wi   = (const float*)d_in[7];
  p.attn_wh   = (const float*)d_in[8];
  p.attn_bi   = (const float*)d_in[9];
  p.attn_bh   = (const float*)d_in[10];
  p.q_w       = (const float*)d_in[11];
  p.k_w       = (const float*)d_in[12];
  p.score_w   = (const float*)d_in[13];
  p.score_b   = (const float*)d_in[14];
  p.conv_w    = (const float*)d_in[15];
  p.loc_w     = (const float*)d_in[16];
  p.loc_b     = (const float*)d_in[17];
  p.out_wi    = (const float*)d_in[18];
  p.out_wh    = (const float*)d_in[19];
  p.out_bi    = (const float*)d_in[20];
  p.out_bh    = (const float*)d_in[21];
  p.dec_w     = (const float*)d_in[22];
  p.dec_b     = (const float*)d_in[23];
  p.gate_w    = (const float*)d_in[24];
  p.gate_b    = (const float*)d_in[25];

  float* ws = (float*)d_ws;
  p.hkeys  = (__half*)(ws);                    // 8,388,608 halfs; dead after prologue
  p.qpart  = ws;                               // reuse: 524,288 floats
  p.melpart = ws + 524288;                     // 131,072 floats
  p.gatepart = ws + 655360;                    // 1,024 floats
  p.gw1T   = (__half*)(ws + 4194304);
  p.gw2T   = (__half*)(ws + 5505024);
  p.pre1T  = (__half*)(ws + 7143424);
  p.pre2T  = (__half*)(ws + 7159808);
  p.locwh  = (__half*)(ws + 7193088);
  p.hA     = ws + 7332352;
  p.hO     = ws + 7365120;
  p.attw   = ws + 7397888;
  p.attcum = ws + 7414272;
  p.decin  = ws + 7430656;
  p.stateZ = p.hA;                             // zero region: hA,hO,attw,attcum,decin = 106,496
  p.ebuf   = ws + 7438848;
  p.zpart  = ws + 7455232;
  p.ctxacc = ws + 7455488;                     // 16384
  p.ctxacc2 = ws + 7472416;                    // 16384
  int* fb  = (int*)(ws + 7488800);             // 2048-int flag region (zeroed via p.zdone)
  p.zdone  = fb;                               // per-bg, x16 stride (8 used)
  p.done2  = fb + 128;
  p.hAdone = fb + 256;
  p.done   = fb + 384;
  p.initbar = fb + 1920;
  float* out = (float*)d_out;
  p.out_mel  = out;
  p.out_gate = out + 1638400;
  p.out_attn = out + 1651200;
  p.out_mask = out + 8204800;

  k_repack<<<2048, 256, 0, stream>>>(p);
  k_keys<<<dim3(128, 8), 512, 0, stream>>>(p);
  void* args[] = { (void*)&p };
  hipLaunchCooperativeKernel((const void*)mega, dim3(NBLK), dim3(NTHR), args, 0, stream);
}

// Round 8
// 37331.821 us; speedup vs baseline: 1.5604x; 1.4284x over previous
//
#include <hip/hip_runtime.h>
#include <hip/hip_fp16.h>
#include <math.h>

#define NBLK 256
#define NTHR 1024

__device__ __forceinline__ float fast_rcp(float x) {
#if __has_builtin(__builtin_amdgcn_rcpf)
  return __builtin_amdgcn_rcpf(x);
#else
  return 1.f / x;
#endif
}
__device__ __forceinline__ float fast_sigmoid(float x) { return fast_rcp(1.f + __expf(-x)); }
__device__ __forceinline__ float fast_tanh(float x) { return 1.f - 2.f * fast_rcp(1.f + __expf(2.f * x)); }

union HU2 { unsigned int u; __half2 h; };
union HU4 { uint4 u; __half2 h[4]; };
__device__ __forceinline__ float2 cvt2(unsigned int u) { HU2 t; t.u = u; return __half22float2(t.h); }

__device__ __forceinline__ void sta(float* p, float v) {
  __hip_atomic_store(p, v, __ATOMIC_RELAXED, __HIP_MEMORY_SCOPE_AGENT);
}
__device__ __forceinline__ float lda(const float* p) {
  return __hip_atomic_load(p, __ATOMIC_RELAXED, __HIP_MEMORY_SCOPE_AGENT);
}
__device__ __forceinline__ int ldai(const int* p) {
  return __hip_atomic_load(p, __ATOMIC_RELAXED, __HIP_MEMORY_SCOPE_AGENT);
}
__device__ __forceinline__ void ntst(float* p, float v) { __builtin_nontemporal_store(v, p); }

struct Params {
  const float *enc, *pre_w1, *pre_w2, *attn_bi, *attn_bh;
  const float *q_w, *k_w, *score_w, *score_b, *conv_w, *loc_w, *loc_b;
  const float *out_bi, *out_bh, *dec_b, *gate_b;
  const float *attn_wi, *attn_wh, *out_wi, *out_wh, *dec_w, *gate_w;
  const int *text_lens, *mel_lens;
  __half *hkeys, *gw1T, *gw2T, *decT, *pre1T, *pre2T, *gateh, *locwh, *qwT;
  float *hA, *hO, *attw, *attcum, *decin, *ebuf, *zpart, *ctxacc, *ctxacc2, *stateZ;
  float *qbuf;
  int *done, *zdone, *done2, *hAdone, *qdone;
  float *out_mel, *out_gate, *out_attn, *out_mask;
};

// ---------------- prep: keys GEMM (fp16 out) ----------------
__global__ __launch_bounds__(512) void k_keys(Params p) {
  __shared__ float sA[16][132];
  __shared__ float sB[16][68];
  int tid = threadIdx.x;
  int row0 = blockIdx.x * 128, col0 = blockIdx.y * 64;
  float acc[4][4] = {};
  int r = tid >> 2, kq = tid & 3;
  int tx = tid & 15, ty = tid >> 4;
  for (int k0 = 0; k0 < 1024; k0 += 16) {
    __syncthreads();
    float4 a4 = *(const float4*)(p.enc + (size_t)(row0 + r) * 1024 + k0 + kq * 4);
    sA[kq * 4 + 0][r] = a4.x; sA[kq * 4 + 1][r] = a4.y;
    sA[kq * 4 + 2][r] = a4.z; sA[kq * 4 + 3][r] = a4.w;
    if (tid < 256) {
      int kb = tid >> 4, nb = (tid & 15) * 4;
      float4 b4 = *(const float4*)(p.k_w + (size_t)(k0 + kb) * 512 + col0 + nb);
      sB[kb][nb + 0] = b4.x; sB[kb][nb + 1] = b4.y;
      sB[kb][nb + 2] = b4.z; sB[kb][nb + 3] = b4.w;
    }
    __syncthreads();
#pragma unroll
    for (int k = 0; k < 16; k++) {
      float ar[4], br[4];
#pragma unroll
      for (int i = 0; i < 4; i++) { ar[i] = sA[k][ty * 4 + i]; br[i] = sB[k][tx * 4 + i]; }
#pragma unroll
      for (int i = 0; i < 4; i++)
#pragma unroll
        for (int j = 0; j < 4; j++) acc[i][j] = fmaf(ar[i], br[j], acc[i][j]);
    }
  }
#pragma unroll
  for (int i = 0; i < 4; i++)
#pragma unroll
    for (int j = 0; j < 4; j++)
      p.hkeys[(size_t)(row0 + ty * 4 + i) * 512 + col0 + tx * 4 + j] = __float2half(acc[i][j]);
}

// ---------------- prep: repack weights + zero state/flags ----------------
__global__ __launch_bounds__(256) void k_repack(Params p) {
  const int gsz = gridDim.x * 256;
  const int t0 = blockIdx.x * 256 + threadIdx.x;
  for (int i = t0; i < 1280 * 512; i += gsz) {
    int r = i >> 9, u = i & 511;
    const float* src = (r < 768) ? p.attn_wi + (size_t)r * 1536 : p.attn_wh + (size_t)(r - 768) * 1536;
    __half2* d = (__half2*)(p.gw1T + ((size_t)i << 2));
    d[0] = __halves2half2(__float2half(src[u]), __float2half(src[512 + u]));
    d[1] = __halves2half2(__float2half(src[1024 + u]), __float2half(0.f));
  }
  for (int i = t0; i < 1536 * 512; i += gsz) {
    int r = i >> 9, u = i & 511;
    const float* src = (r < 1024) ? p.out_wi + (size_t)r * 1536 : p.out_wh + (size_t)(r - 1024) * 1536;
    __half2* d = (__half2*)(p.gw2T + ((size_t)i << 2));
    d[0] = __halves2half2(__float2half(src[u]), __float2half(src[512 + u]));
    d[1] = __halves2half2(__float2half(src[1024 + u]), __float2half(0.f));
  }
  for (int i = t0; i < 512 * 512; i += gsz) {
    int k = i >> 9, a = i & 511;
    p.qwT[(size_t)a * 512 + k] = __float2half(p.q_w[(size_t)k * 512 + a]);
  }
  for (int i = t0; i < 1024 * 128; i += gsz) {
    int k = i >> 7, m = i & 127;
    p.decT[(size_t)m * 1024 + k] = __float2half(p.dec_w[(size_t)k * 128 + m]);
  }
  for (int i = t0; i < 1024; i += gsz) p.gateh[i] = __float2half(p.gate_w[i]);
  for (int i = t0; i < 16384; i += gsz) p.locwh[i] = __float2half(p.loc_w[i]);
  for (int i = t0; i < 128 * 256; i += gsz) {
    int m = i >> 8, pc = i & 255;
    p.pre1T[(size_t)pc * 128 + m] = __float2half(p.pre_w1[(size_t)m * 256 + pc]);
  }
  for (int i = t0; i < 256 * 256; i += gsz) {
    int k = i >> 8, pc = i & 255;
    p.pre2T[(size_t)pc * 256 + k] = __float2half(p.pre_w2[(size_t)k * 256 + pc]);
  }
  for (int i = t0; i < 106496; i += gsz) p.stateZ[i] = 0.f;
  for (int i = t0; i < 16384; i += gsz) p.ctxacc[i] = 0.f;
  for (int i = t0; i < 16384; i += gsz) p.ctxacc2[i] = 0.f;
  for (int i = t0; i < 2048; i += gsz) p.hAdone[i] = 0;   // whole flag region
  for (int i = t0; i < 12800; i += gsz) {
    int b = i / 400, t = i - b * 400;
    p.out_mask[i] = (t > p.mel_lens[b]) ? 1.f : 0.f;
  }
}

struct SMemMega {
  __half keysL[64 * 512];   // persistent P2 keys tile (64 KB)
  float ctxL[4][520];       // persistent ctx
  float hA2[4][520];        // persistent hA_next (staged in P2 tail)
  float hO2[4][520];        // persistent hO_prev (staged in P1f)
  float invZ[4];
  union {
    struct { float x[4][264]; float4 part4[16][64]; } gr;
    struct { float locS[64][33]; float aw[94]; float ac[94]; float hA_s[512];
             float qS[512]; float qp2[16][64]; float cpred[8][512]; float eS[64]; } s3;
    struct { float xh[1024]; float red[1024]; float mel[128]; float p1[256]; } s6;
  } u;
};

// GRU partial accumulation over interleaved rows r = ks + 16*j, j in [j0,j1).
__device__ __forceinline__ void gchunk(const uint2* __restrict__ w,
                                       const float* __restrict__ x, int ks,
                                       int j0, int j1,
                                       float& a0, float& a1, float& a2) {
#pragma unroll 8
  for (int j = j0; j < j1; ++j) {
    uint2 wv = w[(size_t)j << 13];          // + j*16 rows * 512
    float xv = x[ks + (j << 4)];
    float2 f0 = cvt2(wv.x);
    float nf = cvt2(wv.y).x;
    a0 = fmaf(xv, f0.x, a0);
    a1 = fmaf(xv, f0.y, a1);
    a2 = fmaf(xv, nf, a2);
  }
}

__global__ __launch_bounds__(NTHR) void mega(Params p) {
  __shared__ SMemMega sm;
  const int blk = blockIdx.x, tid = threadIdx.x;
  const int ug = blk & 31, bg = blk >> 5, b0 = bg * 4;       // GRU identity
  const int bS = blk & 31, t8 = blk >> 5, t0g = t8 << 6;     // attention identity
  const int bgS = bS >> 2;                                   // bg owning batch bS

  const int u_ = tid & 15, b2_ = (tid >> 4) & 3, ks_ = tid >> 6;
  const int uG_ = (ug << 4) + u_;
  const uint2* w1 = (const uint2*)p.gw1T + ((size_t)ks_ << 9) + uG_;
  const uint2* w2 = (const uint2*)p.gw2T + ((size_t)ks_ << 9) + uG_;

  // ---- one-time: load keys tile into LDS, zero persistent LDS ----
  {
    const uint4* src = (const uint4*)(p.hkeys + (((size_t)(bS << 9) + t0g) << 9));
    uint4* dst = (uint4*)sm.keysL;
    for (int i = tid; i < 4096; i += NTHR) dst[i] = src[i];
    for (int i = tid; i < 2048; i += NTHR) {
      sm.ctxL[i >> 9][i & 511] = 0.f;
      sm.hA2[i >> 9][i & 511] = 0.f;
      sm.hO2[i >> 9][i & 511] = 0.f;
    }
  }
  __syncthreads();

  // GRU1 partial accumulators carried from P3 (prev step) into P1f (this step).
  float g1r = 0.f, g1z = 0.f, g1ni = 0.f, g1nh = 0.f;

#pragma clang loop unroll(disable)
  for (int step = 0; step < 400; step++) {
    const int par = step & 1;
    float* hA_prev = p.hA + par * 16384;
    float* hA_next = p.hA + (par ^ 1) * 16384;
    float* hO_prev = p.hO + par * 16384;
    float* hO_next = p.hO + (par ^ 1) * 16384;
    float* cCur = par ? p.ctxacc2 : p.ctxacc;
    float* cNxt = par ? p.ctxacc : p.ctxacc2;

    // GRU2 partial accumulators for THIS step
    float r2 = 0.f, z2 = 0.f, ni2 = 0.f, nh2 = 0.f;

    // ======== P1f: GRU1 finish (decin rows) + hA + GRU2 hO-part ========
    {
      if (step > 0) {
        if (tid == 0) {
          while (ldai(&p.done2[bg * 16]) < 16 * step)
            __builtin_amdgcn_s_sleep(2);
        }
        __syncthreads();
      }
      for (int i = tid; i < 1024; i += NTHR)
        sm.u.gr.x[i >> 8][i & 255] = lda(&p.decin[((b0 + (i >> 8)) << 8) + (i & 255)]);
      for (int i = tid; i < 2048; i += NTHR)
        sm.hO2[i >> 9][i & 511] = lda(&hO_prev[((b0 + (i >> 9)) << 9) + (i & 511)]);
      __syncthreads();
      gchunk(w1, &sm.u.gr.x[b2_][0], ks_, 0, 16, g1r, g1z, g1ni);  // decin rows 0..255
      sm.u.gr.part4[ks_][(u_ << 2) + b2_] = make_float4(g1r, g1z, g1ni, g1nh);
      __syncthreads();
      if (tid < 64) {
        int uu = tid >> 2, bb2 = tid & 3;
        float4 s = make_float4(0.f, 0.f, 0.f, 0.f);
#pragma unroll
        for (int l = 0; l < 16; l++) {
          float4 v = sm.u.gr.part4[l][(uu << 2) + bb2];
          s.x += v.x; s.y += v.y; s.z += v.z; s.w += v.w;
        }
        int uGf = (ug << 4) + uu;
        float r = fast_sigmoid(s.x + p.attn_bi[uGf] + p.attn_bh[uGf]);
        float z = fast_sigmoid(s.y + p.attn_bi[512 + uGf] + p.attn_bh[512 + uGf]);
        float n = fast_tanh(s.z + p.attn_bi[1024 + uGf] + r * (s.w + p.attn_bh[1024 + uGf]));
        float hv = lda(&hA_prev[((b0 + bb2) << 9) + uGf]);
        sta(&hA_next[((b0 + bb2) << 9) + uGf], (1.f - z) * n + z * hv);
      }
      asm volatile("s_waitcnt vmcnt(0)" ::: "memory");
      if (tid == 0) atomicAdd(&p.hAdone[bg * 16], 1);   // 32/step per bg
      // GRU2 hO-part (rows 1024..1535) from local hO2
      gchunk(w2, &sm.hO2[b2_][0] - 1024, ks_, 64, 96, r2, z2, nh2);
    }

    // ======== P2: pre-wait staging/conv + q-slice + loc-acc + score + ctx ========
    {
      __syncthreads();   // union gr -> s3 transition
      // --- hA-independent work first (gated only by done2(s-1), already passed) ---
      for (int j = tid; j < 94; j += NTHR) {
        int pp = t0g - 15 + j;
        bool ok = (unsigned)pp < 512u;
        sm.u.s3.aw[j] = ok ? lda(&p.attw[(bS << 9) + pp]) : 0.f;
        sm.u.s3.ac[j] = ok ? lda(&p.attcum[(bS << 9) + pp]) : 0.f;
      }
      if (t8 == 0) {
        for (int i = tid; i < 512; i += NTHR) sta(&cNxt[(bS << 9) + i], 0.f);
      }
      __syncthreads();
      const int tlen = p.text_lens[bS];
      for (int i = tid; i < 2048; i += NTHR) {
        int tt = i >> 5, f = i & 31;
        const float* w0 = p.conv_w + f * 62;
        float a = 0.f;
#pragma unroll
        for (int k = 0; k < 31; k++)
          a = fmaf(w0[k], sm.u.s3.aw[tt + k], fmaf(w0[31 + k], sm.u.s3.ac[tt + k], a));
        sm.u.s3.locS[tt][f] = a;
      }
      // --- wait for fresh hA of this batch's bg ---
      if (tid == 0) {
        while (ldai(&p.hAdone[bgS * 16]) < 32 * (step + 1))
          __builtin_amdgcn_s_sleep(2);
      }
      __syncthreads();
      if (tid < 512) sm.u.s3.hA_s[tid] = lda(&hA_next[(bS << 9) + tid]);
      __syncthreads();
      // --- q-slice GEMV: a in [t0g, t0g+64), k split over 16 groups ---
      {
        int a = tid & 63, ks = tid >> 6;   // ks in 0..15
        const HU4* qp = (const HU4*)(p.qwT + (size_t)(t0g + a) * 512 + ks * 32);
        float q0 = 0.f, q1 = 0.f;
#pragma unroll
        for (int it = 0; it < 4; it++) {
          HU4 raw = qp[it];
          int kb = ks * 32 + it * 8;
#pragma unroll
          for (int h2 = 0; h2 < 4; h2++) {
            float2 w = __half22float2(raw.h[h2]);
            q0 = fmaf(sm.u.s3.hA_s[kb + h2 * 2], w.x, q0);
            q1 = fmaf(sm.u.s3.hA_s[kb + h2 * 2 + 1], w.y, q1);
          }
        }
        sm.u.s3.qp2[ks][a] = q0 + q1;
      }
      __syncthreads();
      if (tid < 64) {
        float s = 0.f;
#pragma unroll
        for (int l = 0; l < 16; l++) s += sm.u.s3.qp2[l][tid];
        sta(&p.qbuf[(bS << 9) + t0g + tid], s + p.loc_b[t0g + tid]);
      }
      if (tid == 0) {
        asm volatile("s_waitcnt vmcnt(0)" ::: "memory");
        atomicAdd(&p.qdone[bS * 16], 1);
      }
      // --- loc-only score accumulation (overlaps other blocks' q-slices) ---
      const int lane = tid & 63, wv = tid >> 6;
      float acc[4][8] = {};
#pragma unroll 4
      for (int f = 0; f < 32; f++) {
        HU4 rw; rw.u = *(const uint4*)(p.locwh + (size_t)f * 512 + lane * 8);
        float2 w0 = __half22float2(rw.h[0]), w1 = __half22float2(rw.h[1]);
        float2 w2v = __half22float2(rw.h[2]), w3 = __half22float2(rw.h[3]);
#pragma unroll
        for (int j = 0; j < 4; j++) {
          float lf = sm.u.s3.locS[wv * 4 + j][f];
          acc[j][0] = fmaf(lf, w0.x, acc[j][0]); acc[j][1] = fmaf(lf, w0.y, acc[j][1]);
          acc[j][2] = fmaf(lf, w1.x, acc[j][2]); acc[j][3] = fmaf(lf, w1.y, acc[j][3]);
          acc[j][4] = fmaf(lf, w2v.x, acc[j][4]); acc[j][5] = fmaf(lf, w2v.y, acc[j][5]);
          acc[j][6] = fmaf(lf, w3.x, acc[j][6]); acc[j][7] = fmaf(lf, w3.y, acc[j][7]);
        }
      }
      // --- wait for assembled q, add q + keys ---
      if (tid == 0) {
        while (ldai(&p.qdone[bS * 16]) < 8 * (step + 1))
          __builtin_amdgcn_s_sleep(2);
      }
      __syncthreads();
      if (tid < 512) sm.u.s3.qS[tid] = lda(&p.qbuf[(bS << 9) + tid]);
      __syncthreads();
      float4 qA = *(const float4*)&sm.u.s3.qS[lane * 8];
      float4 qB = *(const float4*)&sm.u.s3.qS[lane * 8 + 4];
#pragma unroll
      for (int j = 0; j < 4; j++) {
        int tL = wv * 4 + j;
        HU4 raw; raw.u = *(const uint4*)&sm.keysL[tL * 512 + lane * 8];
        float2 k0 = __half22float2(raw.h[0]), k1 = __half22float2(raw.h[1]);
        float2 k2 = __half22float2(raw.h[2]), k3 = __half22float2(raw.h[3]);
        acc[j][0] += qA.x + k0.x; acc[j][1] += qA.y + k0.y;
        acc[j][2] += qA.z + k1.x; acc[j][3] += qA.w + k1.y;
        acc[j][4] += qB.x + k2.x; acc[j][5] += qB.y + k2.y;
        acc[j][6] += qB.z + k3.x; acc[j][7] += qB.w + k3.y;
      }
      float4 sA = *(const float4*)(p.score_w + lane * 8);
      float4 sB = *(const float4*)(p.score_w + lane * 8 + 4);
      float sbias = p.score_b[0];
      float e_reg[4];
#pragma unroll
      for (int j = 0; j < 4; j++) {
        float pv = fast_tanh(acc[j][0]) * sA.x + fast_tanh(acc[j][1]) * sA.y +
                   fast_tanh(acc[j][2]) * sA.z + fast_tanh(acc[j][3]) * sA.w +
                   fast_tanh(acc[j][4]) * sB.x + fast_tanh(acc[j][5]) * sB.y +
                   fast_tanh(acc[j][6]) * sB.z + fast_tanh(acc[j][7]) * sB.w;
#pragma unroll
        for (int off = 32; off > 0; off >>= 1) pv += __shfl_xor(pv, off, 64);
        int t = t0g + wv * 4 + j;
        e_reg[j] = (t > tlen) ? 0.f : __expf(pv + sbias);
      }
      if (lane == 0) {
#pragma unroll
        for (int j = 0; j < 4; j++) sm.u.s3.eS[wv * 4 + j] = e_reg[j];
      }
      float cp[8] = {0.f, 0.f, 0.f, 0.f, 0.f, 0.f, 0.f, 0.f};
#pragma unroll
      for (int j = 0; j < 4; j++) {
        int tL = wv * 4 + j;
        HU4 raw; raw.u = *(const uint4*)&sm.keysL[tL * 512 + lane * 8];
        float2 k0 = __half22float2(raw.h[0]), k1 = __half22float2(raw.h[1]);
        float2 k2 = __half22float2(raw.h[2]), k3 = __half22float2(raw.h[3]);
        float e = e_reg[j];
        cp[0] = fmaf(e, k0.x, cp[0]); cp[1] = fmaf(e, k0.y, cp[1]);
        cp[2] = fmaf(e, k1.x, cp[2]); cp[3] = fmaf(e, k1.y, cp[3]);
        cp[4] = fmaf(e, k2.x, cp[4]); cp[5] = fmaf(e, k2.y, cp[5]);
        cp[6] = fmaf(e, k3.x, cp[6]); cp[7] = fmaf(e, k3.y, cp[7]);
      }
      __syncthreads();
      if (wv < 8) {
        float4* r0 = (float4*)&sm.u.s3.cpred[wv][lane * 8];
        r0[0] = make_float4(cp[0], cp[1], cp[2], cp[3]);
        r0[1] = make_float4(cp[4], cp[5], cp[6], cp[7]);
      }
      __syncthreads();
      if (wv >= 8) {
        float* r0 = &sm.u.s3.cpred[wv - 8][lane * 8];
#pragma unroll
        for (int i = 0; i < 8; i++) r0[i] += cp[i];
      }
      __syncthreads();
      if (tid < 512) {
        float s = 0.f;
#pragma unroll
        for (int j = 0; j < 8; j++) s += sm.u.s3.cpred[j][tid];
        atomicAdd(&cCur[(bS << 9) + tid], s);
      }
      if (tid < 64) {
        float e = sm.u.s3.eS[tid];
        sta(&p.ebuf[(bS << 9) + t0g + tid], e);
        float z = e;
#pragma unroll
        for (int off = 32; off > 0; off >>= 1) z += __shfl_xor(z, off, 64);
        if (tid == 0) sta(&p.zpart[bS * 8 + t8], z);
      }
      // per-wave drain + publish (waves 0..7 did all global stores): 8/block
      if (tid < 512 && (tid & 63) == 0) {
        asm volatile("s_waitcnt vmcnt(0)" ::: "memory");
        atomicAdd(&p.zdone[bgS * 16], 1);   // target 256 per bg per step
      }
      // ---- stage hA2 (own bg) + GRU2 hA-part ----
      if (tid == 0) {
        while (ldai(&p.hAdone[bg * 16]) < 32 * (step + 1))
          __builtin_amdgcn_s_sleep(2);
      }
      __syncthreads();
      for (int i = tid; i < 2048; i += NTHR)
        sm.hA2[i >> 9][i & 511] = lda(&hA_next[((b0 + (i >> 9)) << 9) + (i & 511)]);
      __syncthreads();
      gchunk(w2, &sm.hA2[b2_][0], ks_, 0, 32, r2, z2, ni2);   // rows 0..511
    }

    // ======== P3: ctx + GRU2 finish + GRU1-pre + S6 ========
    {
      if (tid == 0) {
        while (ldai(&p.zdone[bg * 16]) < 256 * (step + 1))
          __builtin_amdgcn_s_sleep(2);
      }
      __syncthreads();
      if (tid < 4) {
        float Z = 0.f;
#pragma unroll
        for (int j = 0; j < 8; j++) Z += lda(&p.zpart[(b0 + tid) * 8 + j]);
        sm.invZ[tid] = fast_rcp(Z);
      }
      __syncthreads();
      for (int i = tid; i < 2048; i += NTHR) {
        int b2 = i >> 9, a = i & 511;
        sm.ctxL[b2][a] = lda(&cCur[((b0 + b2) << 9) + a]) * sm.invZ[b2];
      }
      if (ug < 4 && tid < 512) {
        const int bb = b0 + ug;
        float v = lda(&p.ebuf[(bb << 9) + tid]) * sm.invZ[ug];
        sta(&p.attw[(bb << 9) + tid], v);
        float oc = lda(&p.attcum[(bb << 9) + tid]);
        sta(&p.attcum[(bb << 9) + tid], oc + v);
        ntst(&p.out_attn[(size_t)bb * 204800 + (size_t)step * 512 + tid], v);
      }
      __syncthreads();
      gchunk(w2, &sm.ctxL[b2_][0] - 512, ks_, 32, 64, r2, z2, ni2);  // ctx rows
      sm.u.gr.part4[ks_][(u_ << 2) + b2_] = make_float4(r2, z2, ni2, nh2);
      __syncthreads();
      if (tid < 64) {
        int uu = tid >> 2, bb2 = tid & 3;
        float4 s = make_float4(0.f, 0.f, 0.f, 0.f);
#pragma unroll
        for (int l = 0; l < 16; l++) {
          float4 v = sm.u.gr.part4[l][(uu << 2) + bb2];
          s.x += v.x; s.y += v.y; s.z += v.z; s.w += v.w;
        }
        int uGf = (ug << 4) + uu;
        float r = fast_sigmoid(s.x + p.out_bi[uGf] + p.out_bh[uGf]);
        float z = fast_sigmoid(s.y + p.out_bi[512 + uGf] + p.out_bh[512 + uGf]);
        float n = fast_tanh(s.z + p.out_bi[1024 + uGf] + r * (s.w + p.out_bh[1024 + uGf]));
        float hv = sm.hO2[bb2][uGf];
        sta(&hO_next[((b0 + bb2) << 9) + uGf], (1.f - z) * n + z * hv);
      }
      asm volatile("s_waitcnt vmcnt(0)" ::: "memory");
      if (tid == 0) atomicAdd(&p.done[bg * 16], 1);   // 32/step per bg
      // ---- GRU1 pre-accumulation for NEXT step (overlaps done-straggler window) ----
      g1r = 0.f; g1z = 0.f; g1ni = 0.f; g1nh = 0.f;
      if (step < 399) {
        gchunk(w1, &sm.ctxL[b2_][0] - 256, ks_, 16, 48, g1r, g1z, g1ni);
        gchunk(w1, &sm.hA2[b2_][0] - 768, ks_, 48, 80, g1r, g1z, g1nh);
      }
      // ---- S6 (ug<4, own batch) ----
      if (ug < 4) {
        const int bb = b0 + ug;
        if (tid == 0) {
          while (ldai(&p.done[bg * 16]) < 32 * (step + 1))
            __builtin_amdgcn_s_sleep(2);
        }
        __syncthreads();
        sm.u.s6.xh[tid] = (tid < 512) ? lda(&hO_next[(bb << 9) + tid])
                                      : sm.ctxL[ug][tid - 512];
        __syncthreads();
        bool masked = step > p.mel_lens[bb];
        {
          int m = tid & 127, ks = tid >> 7;
          const HU4* dp = (const HU4*)(p.decT + (size_t)m * 1024 + ks * 128);
          float a = 0.f;
#pragma unroll 4
          for (int it = 0; it < 16; it++) {
            HU4 raw = dp[it];
            int kb = ks * 128 + it * 8;
#pragma unroll
            for (int h2 = 0; h2 < 4; h2++) {
              float2 w = __half22float2(raw.h[h2]);
              a = fmaf(sm.u.s6.xh[kb + h2 * 2], w.x, a);
              a = fmaf(sm.u.s6.xh[kb + h2 * 2 + 1], w.y, a);
            }
          }
          sm.u.s6.red[tid] = a;
        }
        __syncthreads();
        if (tid < 128) {
          float mv = p.dec_b[tid];
#pragma unroll
          for (int j = 0; j < 8; j++) mv += sm.u.s6.red[tid + j * 128];
          sm.u.s6.mel[tid] = mv;
          ntst(&p.out_mel[(size_t)bb * 51200 + (size_t)step * 128 + tid], masked ? 0.f : mv);
        }
        __syncthreads();
        sm.u.s6.red[tid] = sm.u.s6.xh[tid] * __half2float(p.gateh[tid]);
        __syncthreads();
        if (tid < 64) {
          float g = 0.f;
#pragma unroll
          for (int j = 0; j < 16; j++) g += sm.u.s6.red[tid + j * 64];
#pragma unroll
          for (int off = 32; off > 0; off >>= 1) g += __shfl_xor(g, off, 64);
          if (tid == 0) ntst(&p.out_gate[bb * 400 + step], masked ? 1000.f : (g + p.gate_b[0]));
        }
        __syncthreads();
        {
          int pc = tid & 255, ks = tid >> 8;
          const HU4* wp = (const HU4*)(p.pre1T + (size_t)pc * 128 + ks * 32);
          float a = 0.f;
#pragma unroll
          for (int it = 0; it < 4; it++) {
            HU4 raw = wp[it];
            int kb = ks * 32 + it * 8;
#pragma unroll
            for (int h2 = 0; h2 < 4; h2++) {
              float2 w = __half22float2(raw.h[h2]);
              a = fmaf(sm.u.s6.mel[kb + h2 * 2], w.x, a);
              a = fmaf(sm.u.s6.mel[kb + h2 * 2 + 1], w.y, a);
            }
          }
          sm.u.s6.red[tid] = a;
        }
        __syncthreads();
        if (tid < 256) {
          float a = sm.u.s6.red[tid] + sm.u.s6.red[tid + 256] +
                    sm.u.s6.red[tid + 512] + sm.u.s6.red[tid + 768];
          sm.u.s6.p1[tid] = fmaxf(a, 0.f);
        }
        __syncthreads();
        {
          int pc = tid & 255, ks = tid >> 8;
          const HU4* wp = (const HU4*)(p.pre2T + (size_t)pc * 256 + ks * 64);
          float a = 0.f;
#pragma unroll
          for (int it = 0; it < 8; it++) {
            HU4 raw = wp[it];
            int kb = ks * 64 + it * 8;
#pragma unroll
            for (int h2 = 0; h2 < 4; h2++) {
              float2 w = __half22float2(raw.h[h2]);
              a = fmaf(sm.u.s6.p1[kb + h2 * 2], w.x, a);
              a = fmaf(sm.u.s6.p1[kb + h2 * 2 + 1], w.y, a);
            }
          }
          sm.u.s6.red[tid] = a;
        }
        __syncthreads();
        if (tid < 256) {
          float a = sm.u.s6.red[tid] + sm.u.s6.red[tid + 256] +
                    sm.u.s6.red[tid + 512] + sm.u.s6.red[tid + 768];
          sta(&p.decin[(bb << 8) + tid], fmaxf(a, 0.f));
        }
        if (tid < 256 && (tid & 63) == 0) {
          asm volatile("s_waitcnt vmcnt(0)" ::: "memory");
          atomicAdd(&p.done2[bg * 16], 1);   // 4/block, 4 blocks -> 16/bg/step
        }
      }
    }
  }
}

extern "C" void kernel_launch(void* const* d_in, const int* in_sizes, int n_in,
                              void* d_out, int out_size, void* d_ws, size_t ws_size,
                              hipStream_t stream) {
  Params p;
  p.enc       = (const float*)d_in[0];
  p.text_lens = (const int*)d_in[2];
  p.mel_lens  = (const int*)d_in[3];
  p.pre_w1    = (const float*)d_in[5];
  p.pre_w2    = (const float*)d_in[6];
  p.attn_wi   = (const float*)d_in[7];
  p.attn_wh   = (const float*)d_in[8];
  p.attn_bi   = (const float*)d_in[9];
  p.attn_bh   = (const float*)d_in[10];
  p.q_w       = (const float*)d_in[11];
  p.k_w       = (const float*)d_in[12];
  p.score_w   = (const float*)d_in[13];
  p.score_b   = (const float*)d_in[14];
  p.conv_w    = (const float*)d_in[15];
  p.loc_w     = (const float*)d_in[16];
  p.loc_b     = (const float*)d_in[17];
  p.out_wi    = (const float*)d_in[18];
  p.out_wh    = (const float*)d_in[19];
  p.out_bi    = (const float*)d_in[20];
  p.out_bh    = (const float*)d_in[21];
  p.dec_w     = (const float*)d_in[22];
  p.dec_b     = (const float*)d_in[23];
  p.gate_w    = (const float*)d_in[24];
  p.gate_b    = (const float*)d_in[25];

  float* ws = (float*)d_ws;
  p.hkeys  = (__half*)(ws);                    // 8,388,608 halfs
  p.gw1T   = (__half*)(ws + 4194304);
  p.gw2T   = (__half*)(ws + 5505024);
  p.decT   = (__half*)(ws + 7077888);
  p.pre1T  = (__half*)(ws + 7143424);
  p.pre2T  = (__half*)(ws + 7159808);
  p.gateh  = (__half*)(ws + 7192576);
  p.locwh  = (__half*)(ws + 7193088);
  p.qwT    = (__half*)(ws + 7201280);
  p.hA     = ws + 7332352;
  p.hO     = ws + 7365120;
  p.attw   = ws + 7397888;
  p.attcum = ws + 7414272;
  p.decin  = ws + 7430656;
  p.stateZ = p.hA;                             // zero region: hA,hO,attw,attcum,decin = 106,496
  p.ebuf   = ws + 7438848;
  p.zpart  = ws + 7455232;
  p.ctxacc = ws + 7455488;                     // 16384
  p.ctxacc2 = ws + 7472416;                    // 16384
  int* fb  = (int*)(ws + 7488800);             // 2048-int flag region
  p.hAdone = fb;                               // per-bg x16 (8 used); repack zeroes 2048 here
  p.zdone  = fb + 128;                         // per-bg x16
  p.done   = fb + 256;                         // per-bg x16
  p.done2  = fb + 384;                         // per-bg x16
  p.qdone  = fb + 512;                         // per-batch x16 (32 used)
  p.qbuf   = ws + 7490848;                     // 16384 floats
  float* out = (float*)d_out;
  p.out_mel  = out;
  p.out_gate = out + 1638400;
  p.out_attn = out + 1651200;
  p.out_mask = out + 8204800;

  k_repack<<<2048, 256, 0, stream>>>(p);
  k_keys<<<dim3(128, 8), 512, 0, stream>>>(p);
  void* args[] = { (void*)&p };
  hipLaunchCooperativeKernel((const void*)mega, dim3(NBLK), dim3(NTHR), args, 0, stream);
}